// Round 1
// baseline (396.837 us; speedup 1.0000x reference)
//
#include <hip/hip_runtime.h>
#include <hip/hip_bf16.h>

typedef __attribute__((ext_vector_type(8))) short bf16x8;
typedef __attribute__((ext_vector_type(4))) short short4v;
typedef __attribute__((ext_vector_type(4))) float f32x4;
typedef __attribute__((ext_vector_type(4))) float float4v;

__device__ __forceinline__ short f2bf(float f) {
    union { float f; unsigned u; } v; v.f = f;
    unsigned r = v.u + 0x7fffu + ((v.u >> 16) & 1u);
    return (short)(r >> 16);
}

// ---------------- GEMM1: QKV = hidden[4096,1024] x w_attn[1024,3072], scatter to Q/K/V bf16 [b][h][s][64]
__global__ __launch_bounds__(256) void qkv_gemm(const float* __restrict__ A,
                                                const float* __restrict__ Bw,
                                                short* __restrict__ Qw,
                                                short* __restrict__ Kw,
                                                short* __restrict__ Vw) {
    __shared__ short As[128 * 64];
    __shared__ short Bs[128 * 64];
    const int tid = threadIdx.x;
    const int l = tid & 63, w = tid >> 6;
    const int g = l >> 4, lr = l & 15;
    const int wm = (w >> 1) * 64, wn = (w & 1) * 64;
    const int m0 = blockIdx.y * 128;
    const int n0 = blockIdx.x * 128;
    const int K = 1024, N = 3072;
    f32x4 acc[4][4] = {};
    for (int k0 = 0; k0 < K; k0 += 64) {
        // stage A tile (fp32 -> bf16), swizzled
#pragma unroll
        for (int i = 0; i < 8; ++i) {
            int idx = i * 256 + tid;
            int row = idx >> 4, s8 = idx & 15;
            float4v a = *reinterpret_cast<const float4v*>(&A[(m0 + row) * K + k0 + s8 * 4]);
            short4v s;
            s[0] = f2bf(a[0]); s[1] = f2bf(a[1]); s[2] = f2bf(a[2]); s[3] = f2bf(a[3]);
            *reinterpret_cast<short4v*>(&As[row * 64 + ((s8 * 4) ^ ((row & 7) << 3))]) = s;
        }
        // stage B tile transposed: Bs[n][k]
#pragma unroll
        for (int i = 0; i < 8; ++i) {
            int idx = i * 256 + tid;
            int kr = idx >> 5, n4 = (idx & 31) * 4;
            float4v bv = *reinterpret_cast<const float4v*>(&Bw[(k0 + kr) * N + n0 + n4]);
#pragma unroll
            for (int c = 0; c < 4; ++c) {
                int n = n4 + c;
                Bs[n * 64 + (kr ^ ((n & 7) << 3))] = f2bf(bv[c]);
            }
        }
        __syncthreads();
#pragma unroll
        for (int kk = 0; kk < 2; ++kk) {
            int ks = kk * 32 + g * 8;
            bf16x8 af[4], bfr[4];
#pragma unroll
            for (int mi = 0; mi < 4; ++mi) {
                int row = wm + mi * 16 + lr;
                af[mi] = *reinterpret_cast<const bf16x8*>(&As[row * 64 + (ks ^ ((row & 7) << 3))]);
            }
#pragma unroll
            for (int ni = 0; ni < 4; ++ni) {
                int col = wn + ni * 16 + lr;
                bfr[ni] = *reinterpret_cast<const bf16x8*>(&Bs[col * 64 + (ks ^ ((col & 7) << 3))]);
            }
#pragma unroll
            for (int mi = 0; mi < 4; ++mi)
#pragma unroll
                for (int ni = 0; ni < 4; ++ni)
                    acc[mi][ni] = __builtin_amdgcn_mfma_f32_16x16x32_bf16(af[mi], bfr[ni], acc[mi][ni], 0, 0, 0);
        }
        __syncthreads();
    }
    // epilogue: scatter into Q/K/V [b][h][s][d] as bf16
#pragma unroll
    for (int mi = 0; mi < 4; ++mi) {
        int mrow = m0 + wm + mi * 16 + g * 4;
#pragma unroll
        for (int ni = 0; ni < 4; ++ni) {
            int n = n0 + wn + ni * 16 + lr;
            int which = n >> 10, h = (n >> 6) & 15, d = n & 63;
            short* dst = (which == 0) ? Qw : ((which == 1) ? Kw : Vw);
#pragma unroll
            for (int r = 0; r < 4; ++r) {
                int m = mrow + r;
                int bb = m >> 11, s = m & 2047;
                dst[((bb * 16 + h) * 2048 + s) * 64 + d] = f2bf(acc[mi][ni][r]);
            }
        }
    }
}

// ---------------- Attention: flash-style, no mask, scale 1/8. Writes merged-head O bf16 [b][s][h*64+d]
__global__ __launch_bounds__(256) void attn_kernel(const short* __restrict__ Qw,
                                                   const short* __restrict__ Kw,
                                                   const short* __restrict__ Vw,
                                                   short* __restrict__ Ow) {
    __shared__ short Ks[64 * 64];
    __shared__ short Vs[64 * 64];   // transposed: Vs[d][key]
    __shared__ short Ps[4][16 * 64];
    const int tid = threadIdx.x;
    const int l = tid & 63, w = tid >> 6;
    const int g = l >> 4, lr = l & 15;
    const int qblk = blockIdx.x, h = blockIdx.y, b = blockIdx.z;
    const int bh = (b * 16 + h) * 2048;
    const int q0 = qblk * 64 + w * 16;

    bf16x8 qa[2];
#pragma unroll
    for (int kk = 0; kk < 2; ++kk)
        qa[kk] = *reinterpret_cast<const bf16x8*>(&Qw[(bh + q0 + lr) * 64 + kk * 32 + g * 8]);

    f32x4 o[4] = {};
    float m_r[4], l_r[4];
#pragma unroll
    for (int r = 0; r < 4; ++r) { m_r[r] = -1e30f; l_r[r] = 0.f; }

    for (int j0 = 0; j0 < 2048; j0 += 64) {
        // stage K (row-major, swizzled) and V (transposed, swizzled)
#pragma unroll
        for (int i = 0; i < 4; ++i) {
            int idx = i * 256 + tid;
            int row = idx >> 4, s8 = idx & 15;
            short4v kv = *reinterpret_cast<const short4v*>(&Kw[(bh + j0 + row) * 64 + s8 * 4]);
            *reinterpret_cast<short4v*>(&Ks[row * 64 + ((s8 * 4) ^ ((row & 7) << 3))]) = kv;
            short4v vv = *reinterpret_cast<const short4v*>(&Vw[(bh + j0 + row) * 64 + s8 * 4]);
#pragma unroll
            for (int c = 0; c < 4; ++c) {
                int d = s8 * 4 + c;
                Vs[d * 64 + (row ^ ((d & 7) << 3))] = vv[c];
            }
        }
        __syncthreads();

        // QK^T: scores 16 x 64 per wave
        f32x4 st[4];
#pragma unroll
        for (int t = 0; t < 4; ++t) {
            f32x4 z = {};
#pragma unroll
            for (int kk = 0; kk < 2; ++kk) {
                int ks = kk * 32 + g * 8;
                int key = t * 16 + lr;
                bf16x8 kb = *reinterpret_cast<const bf16x8*>(&Ks[key * 64 + (ks ^ ((key & 7) << 3))]);
                z = __builtin_amdgcn_mfma_f32_16x16x32_bf16(qa[kk], kb, z, 0, 0, 0);
            }
            st[t] = z * 0.125f;
        }

        // online softmax (wave-parallel, 16-lane groups)
        float rs[4];
#pragma unroll
        for (int r = 0; r < 4; ++r) {
            float mx = fmaxf(fmaxf(st[0][r], st[1][r]), fmaxf(st[2][r], st[3][r]));
#pragma unroll
            for (int off = 1; off < 16; off <<= 1) mx = fmaxf(mx, __shfl_xor(mx, off));
            float mnew = fmaxf(m_r[r], mx);
            float sc = __expf(m_r[r] - mnew);
            m_r[r] = mnew;
            l_r[r] *= sc;
#pragma unroll
            for (int t = 0; t < 4; ++t) o[t][r] *= sc;
            rs[r] = 0.f;
        }
#pragma unroll
        for (int t = 0; t < 4; ++t) {
#pragma unroll
            for (int r = 0; r < 4; ++r) {
                float p = __expf(st[t][r] - m_r[r]);
                rs[r] += p;
                int row = g * 4 + r, col = t * 16 + lr;
                Ps[w][row * 64 + (col ^ ((row & 7) << 3))] = f2bf(p);
            }
        }
#pragma unroll
        for (int r = 0; r < 4; ++r) {
            float s = rs[r];
#pragma unroll
            for (int off = 1; off < 16; off <<= 1) s += __shfl_xor(s, off);
            l_r[r] += s;
        }

        // PV: O[16 x 64] += P[16 x 64] x V[64 x 64]
#pragma unroll
        for (int kk = 0; kk < 2; ++kk) {
            int ks = kk * 32 + g * 8;
            bf16x8 pa = *reinterpret_cast<const bf16x8*>(&Ps[w][lr * 64 + (ks ^ ((lr & 7) << 3))]);
#pragma unroll
            for (int nt = 0; nt < 4; ++nt) {
                int d = nt * 16 + lr;
                bf16x8 vb = *reinterpret_cast<const bf16x8*>(&Vs[d * 64 + (ks ^ ((d & 7) << 3))]);
                o[nt] = __builtin_amdgcn_mfma_f32_16x16x32_bf16(pa, vb, o[nt], 0, 0, 0);
            }
        }
        __syncthreads();
    }

    // finalize + store merged heads
#pragma unroll
    for (int r = 0; r < 4; ++r) {
        float inv = 1.f / l_r[r];
        int s = q0 + g * 4 + r;
#pragma unroll
        for (int nt = 0; nt < 4; ++nt) {
            int d = nt * 16 + lr;
            Ow[(b * 2048 + s) * 1024 + h * 64 + d] = f2bf(o[nt][r] * inv);
        }
    }
}

// ---------------- GEMM2: out = O[4096,1024](bf16) x w_proj[1024,1024](fp32) -> fp32
__global__ __launch_bounds__(256) void proj_gemm(const short* __restrict__ Ag,
                                                 const float* __restrict__ Bw,
                                                 float* __restrict__ Out) {
    __shared__ short As[128 * 64];
    __shared__ short Bs[128 * 64];
    const int tid = threadIdx.x;
    const int l = tid & 63, w = tid >> 6;
    const int g = l >> 4, lr = l & 15;
    const int wm = (w >> 1) * 64, wn = (w & 1) * 64;
    const int m0 = blockIdx.y * 128;
    const int n0 = blockIdx.x * 128;
    const int K = 1024, N = 1024;
    f32x4 acc[4][4] = {};
    for (int k0 = 0; k0 < K; k0 += 64) {
#pragma unroll
        for (int i = 0; i < 8; ++i) {
            int idx = i * 256 + tid;
            int row = idx >> 4, s8 = idx & 15;
            short4v a = *reinterpret_cast<const short4v*>(&Ag[(m0 + row) * K + k0 + s8 * 4]);
            *reinterpret_cast<short4v*>(&As[row * 64 + ((s8 * 4) ^ ((row & 7) << 3))]) = a;
        }
#pragma unroll
        for (int i = 0; i < 8; ++i) {
            int idx = i * 256 + tid;
            int kr = idx >> 5, n4 = (idx & 31) * 4;
            float4v bv = *reinterpret_cast<const float4v*>(&Bw[(k0 + kr) * N + n0 + n4]);
#pragma unroll
            for (int c = 0; c < 4; ++c) {
                int n = n4 + c;
                Bs[n * 64 + (kr ^ ((n & 7) << 3))] = f2bf(bv[c]);
            }
        }
        __syncthreads();
#pragma unroll
        for (int kk = 0; kk < 2; ++kk) {
            int ks = kk * 32 + g * 8;
            bf16x8 af[4], bfr[4];
#pragma unroll
            for (int mi = 0; mi < 4; ++mi) {
                int row = wm + mi * 16 + lr;
                af[mi] = *reinterpret_cast<const bf16x8*>(&As[row * 64 + (ks ^ ((row & 7) << 3))]);
            }
#pragma unroll
            for (int ni = 0; ni < 4; ++ni) {
                int col = wn + ni * 16 + lr;
                bfr[ni] = *reinterpret_cast<const bf16x8*>(&Bs[col * 64 + (ks ^ ((col & 7) << 3))]);
            }
#pragma unroll
            for (int mi = 0; mi < 4; ++mi)
#pragma unroll
                for (int ni = 0; ni < 4; ++ni)
                    acc[mi][ni] = __builtin_amdgcn_mfma_f32_16x16x32_bf16(af[mi], bfr[ni], acc[mi][ni], 0, 0, 0);
        }
        __syncthreads();
    }
#pragma unroll
    for (int mi = 0; mi < 4; ++mi) {
#pragma unroll
        for (int ni = 0; ni < 4; ++ni) {
            int n = n0 + wn + ni * 16 + lr;
#pragma unroll
            for (int r = 0; r < 4; ++r) {
                int m = m0 + wm + mi * 16 + g * 4 + r;
                Out[m * N + n] = acc[mi][ni][r];
            }
        }
    }
}

extern "C" void kernel_launch(void* const* d_in, const int* in_sizes, int n_in,
                              void* d_out, int out_size, void* d_ws, size_t ws_size,
                              hipStream_t stream) {
    const float* hidden = (const float*)d_in[0];
    const float* w_attn = (const float*)d_in[1];
    const float* w_proj = (const float*)d_in[2];
    float* out = (float*)d_out;

    // ws layout (bf16 as short): Q | K | V | O, each [2][16][2048][64] / O = [4096][1024]
    short* Qw = (short*)d_ws;
    short* Kw = Qw + 4194304;
    short* Vw = Kw + 4194304;
    short* Ow = Vw + 4194304;   // total 32 MiB

    qkv_gemm<<<dim3(24, 32), 256, 0, stream>>>(hidden, w_attn, Qw, Kw, Vw);
    attn_kernel<<<dim3(32, 16, 2), 256, 0, stream>>>(Qw, Kw, Vw, Ow);
    proj_gemm<<<dim3(8, 32), 256, 0, stream>>>(Ow, w_proj, out);
}

// Round 2
// 329.273 us; speedup vs baseline: 1.2052x; 1.2052x over previous
//
#include <hip/hip_runtime.h>
#include <hip/hip_bf16.h>

typedef __attribute__((ext_vector_type(8))) short bf16x8;
typedef __attribute__((ext_vector_type(4))) short short4v;
typedef __attribute__((ext_vector_type(4))) float f32x4;
typedef __attribute__((ext_vector_type(4))) float float4v;

__device__ __forceinline__ short f2bf(float f) {
    union { float f; unsigned u; } v; v.f = f;
    unsigned r = v.u + 0x7fffu + ((v.u >> 16) & 1u);
    return (short)(r >> 16);
}

// ---------------- GEMM1: QKV = hidden[4096,1024] x w_attn[1024,3072]
// Writes Q (pre-scaled by 1/8), K as [b][h][s][64] bf16; V as V^T [b][h][64][2048] bf16.
__global__ __launch_bounds__(256) void qkv_gemm(const float* __restrict__ A,
                                                const float* __restrict__ Bw,
                                                short* __restrict__ Qw,
                                                short* __restrict__ Kw,
                                                short* __restrict__ Vt) {
    __shared__ short As[128 * 64];
    __shared__ short Bs[128 * 64];
    const int tid = threadIdx.x;
    const int l = tid & 63, w = tid >> 6;
    const int g = l >> 4, lr = l & 15;
    const int wm = (w >> 1) * 64, wn = (w & 1) * 64;
    const int m0 = blockIdx.y * 128;
    const int n0 = blockIdx.x * 128;
    const int K = 1024, N = 3072;
    f32x4 acc[4][4] = {};
    for (int k0 = 0; k0 < K; k0 += 64) {
        // stage A tile (fp32 -> bf16): granule = 8 k-elems, swizzled b128 write
#pragma unroll
        for (int i = 0; i < 4; ++i) {
            int gi = i * 256 + tid;
            int row = gi >> 3, gr = gi & 7;
            const float* src = &A[(m0 + row) * K + k0 + gr * 8];
            float4v a0 = *reinterpret_cast<const float4v*>(src);
            float4v a1 = *reinterpret_cast<const float4v*>(src + 4);
            bf16x8 s;
            s[0] = f2bf(a0[0]); s[1] = f2bf(a0[1]); s[2] = f2bf(a0[2]); s[3] = f2bf(a0[3]);
            s[4] = f2bf(a1[0]); s[5] = f2bf(a1[1]); s[6] = f2bf(a1[2]); s[7] = f2bf(a1[3]);
            *reinterpret_cast<bf16x8*>(&As[row * 64 + ((gr ^ (row & 7)) * 8)]) = s;
        }
        // stage B tile as [n][k]: n-coalesced scalar loads, swizzled b128 write
#pragma unroll
        for (int i = 0; i < 4; ++i) {
            int gi = i * 256 + tid;
            int n = gi & 127, gk = gi >> 7;
            bf16x8 s;
#pragma unroll
            for (int j = 0; j < 8; ++j)
                s[j] = f2bf(Bw[(k0 + gk * 8 + j) * N + n0 + n]);
            *reinterpret_cast<bf16x8*>(&Bs[n * 64 + ((gk ^ (n & 7)) * 8)]) = s;
        }
        __syncthreads();
#pragma unroll
        for (int kk = 0; kk < 2; ++kk) {
            int ks = kk * 32 + g * 8;
            bf16x8 af[4], bfr[4];
#pragma unroll
            for (int mi = 0; mi < 4; ++mi) {
                int row = wm + mi * 16 + lr;
                af[mi] = *reinterpret_cast<const bf16x8*>(&As[row * 64 + (ks ^ ((row & 7) << 3))]);
            }
#pragma unroll
            for (int ni = 0; ni < 4; ++ni) {
                int col = wn + ni * 16 + lr;
                bfr[ni] = *reinterpret_cast<const bf16x8*>(&Bs[col * 64 + (ks ^ ((col & 7) << 3))]);
            }
#pragma unroll
            for (int mi = 0; mi < 4; ++mi)
#pragma unroll
                for (int ni = 0; ni < 4; ++ni)
                    acc[mi][ni] = __builtin_amdgcn_mfma_f32_16x16x32_bf16(af[mi], bfr[ni], acc[mi][ni], 0, 0, 0);
        }
        __syncthreads();
    }
    // epilogue
#pragma unroll
    for (int mi = 0; mi < 4; ++mi) {
        int m = m0 + wm + mi * 16 + g * 4;
        int bb = m >> 11, s0 = m & 2047;
#pragma unroll
        for (int ni = 0; ni < 4; ++ni) {
            int n = n0 + wn + ni * 16 + lr;
            int which = n >> 10, hh = (n >> 6) & 15, d = n & 63;
            if (which == 2) {
                short4v pv;
#pragma unroll
                for (int r = 0; r < 4; ++r) pv[r] = f2bf(acc[mi][ni][r]);
                *reinterpret_cast<short4v*>(&Vt[(((bb * 16 + hh) * 64) + d) * 2048 + s0]) = pv;
            } else {
                short* dst = which ? Kw : Qw;
                float sc = which ? 1.0f : 0.125f;
#pragma unroll
                for (int r = 0; r < 4; ++r)
                    dst[((bb * 16 + hh) * 2048 + s0 + r) * 64 + d] = f2bf(acc[mi][ni][r] * sc);
            }
        }
    }
}

// ---------------- Attention v2: LDS-free, swapped QK^T, in-register softmax.
// Q pre-scaled. Reads K [b][h][s][64], V^T [b][h][64][2048]. Writes merged O bf16 [b][s][1024].
__global__ __launch_bounds__(256) void attn2(const short* __restrict__ Qw,
                                             const short* __restrict__ Kw,
                                             const short* __restrict__ Vt,
                                             short* __restrict__ Ow) {
    const int tid = threadIdx.x;
    const int w = tid >> 6, l = tid & 63;
    const int g = l >> 4, lr = l & 15;
    const int wid = blockIdx.x * 4 + w;      // 0..4095
    const int qt = wid & 127, h = (wid >> 7) & 15, b = wid >> 11;
    const short* Qb = Qw + ((b * 16 + h) * 2048 + qt * 16) * 64;
    const short* Kb = Kw + ((b * 16 + h) * 2048) * 64;
    const short* Vb = Vt + ((b * 16 + h) * 64) * 2048;

    bf16x8 qa[2];
    qa[0] = *reinterpret_cast<const bf16x8*>(&Qb[lr * 64 + g * 8]);
    qa[1] = *reinterpret_cast<const bf16x8*>(&Qb[lr * 64 + 32 + g * 8]);

    f32x4 o[4] = {};
    float m = -1e30f, lsum = 0.f;

    for (int j0 = 0; j0 < 2048; j0 += 64) {
        // K fragments (A-operand): lane holds key-row = j0 + t*16 + lr, k = kk*32+g*8..+7
        bf16x8 kb[4][2];
#pragma unroll
        for (int t = 0; t < 4; ++t)
#pragma unroll
            for (int kk = 0; kk < 2; ++kk)
                kb[t][kk] = *reinterpret_cast<const bf16x8*>(&Kb[(j0 + t * 16 + lr) * 64 + kk * 32 + g * 8]);
        // V^T fragments (A-operand of PV): lane holds d-row = dt*16+lr, keys kk*32+g*8..+7
        bf16x8 vb[2][4];
#pragma unroll
        for (int kk = 0; kk < 2; ++kk)
#pragma unroll
            for (int dt = 0; dt < 4; ++dt)
                vb[kk][dt] = *reinterpret_cast<const bf16x8*>(&Vb[(dt * 16 + lr) * 2048 + j0 + kk * 32 + g * 8]);

        // swapped QK^T: st[t] = S^T tile, lane: col q = lr, rows key = t*16 + g*4 + r
        f32x4 st[4];
#pragma unroll
        for (int t = 0; t < 4; ++t) {
            f32x4 z = {};
            z = __builtin_amdgcn_mfma_f32_16x16x32_bf16(kb[t][0], qa[0], z, 0, 0, 0);
            z = __builtin_amdgcn_mfma_f32_16x16x32_bf16(kb[t][1], qa[1], z, 0, 0, 0);
            st[t] = z;
        }

        // in-register online softmax (per lane: 16 of the 64 keys of query lr)
        float mloc = st[0][0];
#pragma unroll
        for (int t = 0; t < 4; ++t)
#pragma unroll
            for (int r = 0; r < 4; ++r) mloc = fmaxf(mloc, st[t][r]);
        mloc = fmaxf(mloc, __shfl_xor(mloc, 16));
        mloc = fmaxf(mloc, __shfl_xor(mloc, 32));
        float mnew = fmaxf(m, mloc);
        float sc = __expf(m - mnew);
        m = mnew;

        float ps = 0.f;
        int pk[4][2];
#pragma unroll
        for (int t = 0; t < 4; ++t)
#pragma unroll
            for (int rr = 0; rr < 2; ++rr) {
                float p0 = __expf(st[t][2 * rr] - m);
                float p1 = __expf(st[t][2 * rr + 1] - m);
                ps += p0 + p1;
                pk[t][rr] = (int)(((unsigned)(unsigned short)f2bf(p1) << 16) | (unsigned)(unsigned short)f2bf(p0));
            }
        ps += __shfl_xor(ps, 16);
        ps += __shfl_xor(ps, 32);
        lsum = lsum * sc + ps;
#pragma unroll
        for (int t = 0; t < 4; ++t) o[t] *= sc;

        // exchange P^T -> PV B-fragments. dest word w (keys j=2w,2w+1 of kk*32+g*8+j):
        //   src lane = (2*(g&1) + (w>>1))*16 + lr ; src word = pk[2kk + (g>>1)][w&1]
        const int base0 = ((g & 1) * 2) * 16 + lr;
        const int base1 = base0 + 16;
        const bool hi = (g >> 1) != 0;
#pragma unroll
        for (int kk = 0; kk < 2; ++kk) {
            int aw0 = __shfl(pk[2 * kk][0], base0), bw0 = __shfl(pk[2 * kk + 1][0], base0);
            int aw1 = __shfl(pk[2 * kk][1], base0), bw1 = __shfl(pk[2 * kk + 1][1], base0);
            int aw2 = __shfl(pk[2 * kk][0], base1), bw2 = __shfl(pk[2 * kk + 1][0], base1);
            int aw3 = __shfl(pk[2 * kk][1], base1), bw3 = __shfl(pk[2 * kk + 1][1], base1);
            union { bf16x8 v; int w4[4]; } bu;
            bu.w4[0] = hi ? bw0 : aw0;
            bu.w4[1] = hi ? bw1 : aw1;
            bu.w4[2] = hi ? bw2 : aw2;
            bu.w4[3] = hi ? bw3 : aw3;
#pragma unroll
            for (int dt = 0; dt < 4; ++dt)
                o[dt] = __builtin_amdgcn_mfma_f32_16x16x32_bf16(vb[kk][dt], bu.v, o[dt], 0, 0, 0);
        }
    }

    // finalize: O^T lane holds q = lr, d = dt*16 + g*4 + r
    float inv = 1.f / lsum;
    int s = qt * 16 + lr;
#pragma unroll
    for (int dt = 0; dt < 4; ++dt) {
        short4v ov;
#pragma unroll
        for (int r = 0; r < 4; ++r) ov[r] = f2bf(o[dt][r] * inv);
        *reinterpret_cast<short4v*>(&Ow[(b * 2048 + s) * 1024 + h * 64 + dt * 16 + g * 4]) = ov;
    }
}

// ---------------- GEMM2: out = O[4096,1024](bf16) x w_proj[1024,1024](fp32) -> fp32
__global__ __launch_bounds__(256) void proj_gemm(const short* __restrict__ Ag,
                                                 const float* __restrict__ Bw,
                                                 float* __restrict__ Out) {
    __shared__ short As[128 * 64];
    __shared__ short Bs[128 * 64];
    const int tid = threadIdx.x;
    const int l = tid & 63, w = tid >> 6;
    const int g = l >> 4, lr = l & 15;
    const int wm = (w >> 1) * 64, wn = (w & 1) * 64;
    const int m0 = blockIdx.y * 128;
    const int n0 = blockIdx.x * 128;
    const int K = 1024, N = 1024;
    f32x4 acc[4][4] = {};
    for (int k0 = 0; k0 < K; k0 += 64) {
#pragma unroll
        for (int i = 0; i < 4; ++i) {
            int gi = i * 256 + tid;
            int row = gi >> 3, gr = gi & 7;
            bf16x8 s = *reinterpret_cast<const bf16x8*>(&Ag[(m0 + row) * K + k0 + gr * 8]);
            *reinterpret_cast<bf16x8*>(&As[row * 64 + ((gr ^ (row & 7)) * 8)]) = s;
        }
#pragma unroll
        for (int i = 0; i < 4; ++i) {
            int gi = i * 256 + tid;
            int n = gi & 127, gk = gi >> 7;
            bf16x8 s;
#pragma unroll
            for (int j = 0; j < 8; ++j)
                s[j] = f2bf(Bw[(k0 + gk * 8 + j) * N + n0 + n]);
            *reinterpret_cast<bf16x8*>(&Bs[n * 64 + ((gk ^ (n & 7)) * 8)]) = s;
        }
        __syncthreads();
#pragma unroll
        for (int kk = 0; kk < 2; ++kk) {
            int ks = kk * 32 + g * 8;
            bf16x8 af[4], bfr[4];
#pragma unroll
            for (int mi = 0; mi < 4; ++mi) {
                int row = wm + mi * 16 + lr;
                af[mi] = *reinterpret_cast<const bf16x8*>(&As[row * 64 + (ks ^ ((row & 7) << 3))]);
            }
#pragma unroll
            for (int ni = 0; ni < 4; ++ni) {
                int col = wn + ni * 16 + lr;
                bfr[ni] = *reinterpret_cast<const bf16x8*>(&Bs[col * 64 + (ks ^ ((col & 7) << 3))]);
            }
#pragma unroll
            for (int mi = 0; mi < 4; ++mi)
#pragma unroll
                for (int ni = 0; ni < 4; ++ni)
                    acc[mi][ni] = __builtin_amdgcn_mfma_f32_16x16x32_bf16(af[mi], bfr[ni], acc[mi][ni], 0, 0, 0);
        }
        __syncthreads();
    }
#pragma unroll
    for (int mi = 0; mi < 4; ++mi) {
#pragma unroll
        for (int ni = 0; ni < 4; ++ni) {
            int n = n0 + wn + ni * 16 + lr;
#pragma unroll
            for (int r = 0; r < 4; ++r) {
                int mm = m0 + wm + mi * 16 + g * 4 + r;
                Out[mm * N + n] = acc[mi][ni][r];
            }
        }
    }
}

extern "C" void kernel_launch(void* const* d_in, const int* in_sizes, int n_in,
                              void* d_out, int out_size, void* d_ws, size_t ws_size,
                              hipStream_t stream) {
    const float* hidden = (const float*)d_in[0];
    const float* w_attn = (const float*)d_in[1];
    const float* w_proj = (const float*)d_in[2];
    float* out = (float*)d_out;

    // ws layout (bf16 as short): Q | K | V^T | O  (8 MiB each, 32 MiB total)
    short* Qw = (short*)d_ws;
    short* Kw = Qw + 4194304;
    short* Vt = Kw + 4194304;
    short* Ow = Vt + 4194304;

    qkv_gemm<<<dim3(24, 32), 256, 0, stream>>>(hidden, w_attn, Qw, Kw, Vt);
    attn2<<<dim3(1024), 256, 0, stream>>>(Qw, Kw, Vt, Ow);
    proj_gemm<<<dim3(8, 32), 256, 0, stream>>>(Ow, w_proj, out);
}